// Round 10
// baseline (121.039 us; speedup 1.0000x reference)
//
#include <hip/hip_runtime.h>
#include <hip/hip_bf16.h>

typedef _Float16 half2v __attribute__((ext_vector_type(2)));
typedef _Float16 half8 __attribute__((ext_vector_type(8)));
typedef __attribute__((ext_vector_type(4))) float floatx4;
typedef __attribute__((ext_vector_type(4))) unsigned int uintx4;

#define GLOBAL_AS __attribute__((address_space(1)))
#define LDS_AS __attribute__((address_space(3)))

// async 16B/lane global->LDS DMA. LDS dest = WAVE-uniform base + lane*16.
__device__ __forceinline__ void async_ld16(const void* g, void* l) {
  __builtin_amdgcn_global_load_lds((const GLOBAL_AS unsigned int*)g,
                                   (LDS_AS unsigned int*)l, 16, 0, 0);
}

__device__ __forceinline__ half2v h2(float v) {
  return (half2v){(_Float16)v, (_Float16)v};
}

// tanh(x0),tanh(x1) -> packed-f16 Legendre P1..P8 for BOTH elements.
// fa0 = low halves (elem0), fa1 = high halves (elem1). ~42 VALU total.
__device__ __forceinline__ void legendre2_f16(float xv0, float xv1,
                                              half8* fa0, half8* fa1) {
  float e0 = __builtin_amdgcn_exp2f(xv0 * 2.885390081777927f); // 2*log2(e)
  float t0 = 1.0f - 2.0f * __builtin_amdgcn_rcpf(e0 + 1.0f);
  float e1 = __builtin_amdgcn_exp2f(xv1 * 2.885390081777927f);
  float t1 = 1.0f - 2.0f * __builtin_amdgcn_rcpf(e1 + 1.0f);
  half2v t;
  { auto tt = __builtin_amdgcn_cvt_pkrtz(t0, t1); __builtin_memcpy(&t, &tt, 4); }
  // P_k = u + c_k*(u - P_{k-2}), u = t*P_{k-1}, c_k=(k-1)/k   (packed, 3 ops/deg)
  half2v p1 = t;
  half2v u2 = t * p1, w2 = u2 - h2(1.0f);  half2v p2 = h2(0.5f)      * w2 + u2;
  half2v u3 = t * p2, w3 = u3 - p1;        half2v p3 = h2(2.0f/3.0f) * w3 + u3;
  half2v u4 = t * p3, w4 = u4 - p2;        half2v p4 = h2(0.75f)     * w4 + u4;
  half2v u5 = t * p4, w5 = u5 - p3;        half2v p5 = h2(0.8f)      * w5 + u5;
  half2v u6 = t * p5, w6 = u6 - p4;        half2v p6 = h2(5.0f/6.0f) * w6 + u6;
  half2v u7 = t * p6, w7 = u7 - p5;        half2v p7 = h2(6.0f/7.0f) * w7 + u7;
  half2v u8 = t * p7, w8 = u8 - p6;        half2v p8 = h2(7.0f/8.0f) * w8 + u8;
  unsigned P[8];
  __builtin_memcpy(&P[0], &p1, 4); __builtin_memcpy(&P[1], &p2, 4);
  __builtin_memcpy(&P[2], &p3, 4); __builtin_memcpy(&P[3], &p4, 4);
  __builtin_memcpy(&P[4], &p5, 4); __builtin_memcpy(&P[5], &p6, 4);
  __builtin_memcpy(&P[6], &p7, 4); __builtin_memcpy(&P[7], &p8, 4);
  union { unsigned u[4]; half8 h; } a0, a1;
#pragma unroll
  for (int j = 0; j < 4; ++j) {
    a0.u[j] = __builtin_amdgcn_perm(P[2*j+1], P[2*j], 0x05040100u); // low halves
    a1.u[j] = __builtin_amdgcn_perm(P[2*j+1], P[2*j], 0x07060302u); // high halves
  }
  *fa0 = a0.h;
  *fa1 = a1.h;
}

// ---- kernel 1: c_basis fp32 -> f16, transposed to ws[i][o][d] (256 KB) ----
__global__ void conv_kernel(const float* __restrict__ cb, _Float16* __restrict__ ws) {
  int t = blockIdx.x * 128 + threadIdx.x;   // 0..16383 = (o,i)
  int o = t >> 8;
  int i = t & 255;
  const floatx4* s = (const floatx4*)(cb + ((size_t)o * 256 + i) * 8);
  floatx4 v0 = s[0], v1 = s[1];
  union { _Float16 h[8]; uintx4 u; } w;
  w.h[0] = (_Float16)v0.x; w.h[1] = (_Float16)v0.y;
  w.h[2] = (_Float16)v0.z; w.h[3] = (_Float16)v0.w;
  w.h[4] = (_Float16)v1.x; w.h[5] = (_Float16)v1.y;
  w.h[6] = (_Float16)v1.z; w.h[7] = (_Float16)v1.w;
  *(uintx4*)(ws + (size_t)i * 512 + o * 8) = w.u;
}

// ---- kernel 2: R9 skeleton + legendre pipelined ONE STEP AHEAD ----
// 512 thr = 8 waves, wave wid owns rows rb+wid*32..+31, FULL K=256.
// Grid 256 -> 1 block/CU, LDS 96 KB, triple-buffer depth-2 staging.
// NEW vs R9: during step ch, the wave computes legendre fragments f(ch+1)
// from xs[(ch+1)%3] into registers — independent of step ch's MFMAs, so the
// ~400 VALU cyc/step interleave into the MFMA shadow (breaks the serial
// x->legendre->MFMA chain). KEY SAFETY FACT: each wave stages its OWN 32
// rows' x units (u = wid*128 + k*64 + lane -> rows wid*32..+31), so the
// ahead-read is self-staged: own vmcnt gate suffices, no extra barrier.
// Gate = vmcnt(4): at step ch (after issuing stage(ch+2)) outstanding =
// {stage(ch+1), stage(ch+2)} = 8 -> drains stage(ch+1) (x-ahead RAW) and a
// fortiori stage(ch) (B RAW for this step's MFMA). Steps 14/15: vmcnt(0).
// Buffer WAR re-verified: stage(ch+2) writes buf (ch-1)%3; its x part was
// last read at step ch-2 (legendre for ch-1), its B part at step ch-1 —
// both behind the top-of-step-ch barrier. All maps R9-verified (passing).
// Epilogue: direct store + bias (no reduction).
#define NSTEP 16

__global__ __launch_bounds__(512, 2) void kan_kernel(
    const float* __restrict__ x, const _Float16* __restrict__ ws,
    const float* __restrict__ bias, float* __restrict__ y) {
  __shared__ __align__(16) _Float16 bt[3][8192]; // 16 slots x 512h, 3 bufs: 48 KB
  __shared__ __align__(16) float xs[3][4096];    // 256 rows x 16 cols, 3 bufs: 48 KB

  const int tid  = threadIdx.x;
  const int wid  = tid >> 6;     // 0..7 = row-eighth (32 rows)
  const int lane = tid & 63;
  const int m    = lane & 15;
  const int q    = lane >> 4;
  const int rb   = blockIdx.x * 256;

  floatx4 acc[2][4];
#pragma unroll
  for (int a = 0; a < 2; ++a)
#pragma unroll
    for (int nt = 0; nt < 4; ++nt) acc[a][nt] = (floatx4){0.f, 0.f, 0.f, 0.f};

  // B DMA src: slots t = wid*2, wid*2+1; i-row i = step*16 + t (1 KB each)
  const _Float16* bsrc0 = ws + (size_t)(wid * 2 + 0) * 512 + lane * 8;
  const _Float16* bsrc1 = ws + (size_t)(wid * 2 + 1) * 512 + lane * 8;

  // x DMA src: 2 units/lane: u = wid*128 + k*64 + lane; row = u>>2 (OWN rows
  // wid*32..+31), stored piece p' = u&3, global piece p = p' ^ ((row>>1)&3)
  const float* xsrc0;
  const float* xsrc1;
  {
    int u0 = wid * 128 + lane;
    int r0_ = u0 >> 2, p0 = (u0 & 3) ^ ((r0_ >> 1) & 3);
    xsrc0 = x + (size_t)(rb + r0_) * 256 + p0 * 4;
    int u1 = wid * 128 + 64 + lane;
    int r1_ = u1 >> 2, p1 = (u1 & 3) ^ ((r1_ >> 1) & 3);
    xsrc1 = x + (size_t)(rb + r1_) * 256 + p1 * 4;
  }

  // 4 DMAs per wave per stage call: 2 B i-rows + 2 x unit-blocks (1 KB each)
  auto stage = [&](int b) {
    async_ld16(bsrc0, &bt[b][(wid * 2 + 0) * 512]);
    async_ld16(bsrc1, &bt[b][(wid * 2 + 1) * 512]);
    bsrc0 += 8192; bsrc1 += 8192;                 // +16 i-rows
    async_ld16(xsrc0, &xs[b][wid * 512]);
    async_ld16(xsrc1, &xs[b][wid * 512 + 256]);
    xsrc0 += 16; xsrc1 += 16;                     // +16 cols
  };

  stage(0);          // step 0 -> buf 0
  stage(1);          // step 1 -> buf 1   (8 DMAs in flight)

  const int row0 = wid * 32 + m;         // row-stream 0 (stream 1 = +16)
  const int sw   = (m >> 1) & 3;         // x swizzle key ((row0>>1)&3)

  // legendre fragment double-state: fc = current step, fn = next step
  half8 fc0[4], fc1[4], fn0[4], fn1[4];

  // prologue: drain stage(0) (own x units included), legendre for step 0
  asm volatile("s_waitcnt vmcnt(4)" ::: "memory");
#pragma unroll
  for (int ks = 0; ks < 4; ++ks) {
    const int xi = row0 * 16 + ((ks ^ sw) << 2) + q;
    legendre2_f16(xs[0][xi], xs[0][xi + 256], &fc0[ks], &fc1[ks]);
  }

#define STEP(ch, N, LAST)                                                      \
  {                                                                            \
    asm volatile("s_barrier" ::: "memory");                                    \
    if constexpr ((ch) + 2 < NSTEP) stage(((ch) + 2) % 3);                     \
    asm volatile("s_waitcnt vmcnt(" #N ")" ::: "memory");                      \
    asm volatile("s_barrier" ::: "memory");                                    \
    _Pragma("unroll")                                                          \
    for (int ks = 0; ks < 4; ++ks) {                                           \
      const _Float16* bp = &bt[(ch) % 3][(ks * 4 + q) * 512 + m * 8];          \
      half8 fb0 = *(const half8*)(bp + 0);                                     \
      half8 fb1 = *(const half8*)(bp + 128);                                   \
      half8 fb2 = *(const half8*)(bp + 256);                                   \
      half8 fb3 = *(const half8*)(bp + 384);                                   \
      if constexpr (!(LAST)) {                                                 \
        const int xi = row0 * 16 + ((ks ^ sw) << 2) + q;                       \
        legendre2_f16(xs[((ch) + 1) % 3][xi], xs[((ch) + 1) % 3][xi + 256],    \
                      &fn0[ks], &fn1[ks]);                                     \
      }                                                                        \
      __builtin_amdgcn_s_setprio(1);                                           \
      acc[0][0] = __builtin_amdgcn_mfma_f32_16x16x32_f16(fc0[ks], fb0, acc[0][0], 0, 0, 0); \
      acc[1][0] = __builtin_amdgcn_mfma_f32_16x16x32_f16(fc1[ks], fb0, acc[1][0], 0, 0, 0); \
      acc[0][1] = __builtin_amdgcn_mfma_f32_16x16x32_f16(fc0[ks], fb1, acc[0][1], 0, 0, 0); \
      acc[1][1] = __builtin_amdgcn_mfma_f32_16x16x32_f16(fc1[ks], fb1, acc[1][1], 0, 0, 0); \
      acc[0][2] = __builtin_amdgcn_mfma_f32_16x16x32_f16(fc0[ks], fb2, acc[0][2], 0, 0, 0); \
      acc[1][2] = __builtin_amdgcn_mfma_f32_16x16x32_f16(fc1[ks], fb2, acc[1][2], 0, 0, 0); \
      acc[0][3] = __builtin_amdgcn_mfma_f32_16x16x32_f16(fc0[ks], fb3, acc[0][3], 0, 0, 0); \
      acc[1][3] = __builtin_amdgcn_mfma_f32_16x16x32_f16(fc1[ks], fb3, acc[1][3], 0, 0, 0); \
      __builtin_amdgcn_s_setprio(0);                                           \
    }                                                                          \
    if constexpr (!(LAST)) {                                                   \
      _Pragma("unroll")                                                        \
      for (int ks = 0; ks < 4; ++ks) { fc0[ks] = fn0[ks]; fc1[ks] = fn1[ks]; } \
    }                                                                          \
  }

  STEP(0, 4, 0)  STEP(1, 4, 0)  STEP(2, 4, 0)  STEP(3, 4, 0)
  STEP(4, 4, 0)  STEP(5, 4, 0)  STEP(6, 4, 0)  STEP(7, 4, 0)
  STEP(8, 4, 0)  STEP(9, 4, 0)  STEP(10, 4, 0) STEP(11, 4, 0)
  STEP(12, 4, 0) STEP(13, 4, 0) STEP(14, 0, 0) STEP(15, 0, 1)
#undef STEP

  // ---- epilogue: direct store + bias (no reduction — full K per wave) ----
  float bv[4];
#pragma unroll
  for (int nt = 0; nt < 4; ++nt) bv[nt] = bias[nt * 16 + m];
#pragma unroll
  for (int a = 0; a < 2; ++a) {
    int gr0 = rb + wid * 32 + a * 16 + q * 4;
#pragma unroll
    for (int nt = 0; nt < 4; ++nt) {
#pragma unroll
      for (int r = 0; r < 4; ++r) {
        y[(size_t)(gr0 + r) * 64 + nt * 16 + m] = acc[a][nt][r] + bv[nt];
      }
    }
  }
}

extern "C" void kernel_launch(void* const* d_in, const int* in_sizes, int n_in,
                              void* d_out, int out_size, void* d_ws, size_t ws_size,
                              hipStream_t stream) {
  const float* x    = (const float*)d_in[0];
  const float* cb   = (const float*)d_in[1];
  const float* bias = (const float*)d_in[2];
  float* y = (float*)d_out;
  _Float16* ws = (_Float16*)d_ws;
  int batch = in_sizes[0] / 256;  // 65536
  hipLaunchKernelGGL(conv_kernel, dim3(128), dim3(128), 0, stream, cb, ws);
  hipLaunchKernelGGL(kan_kernel, dim3(batch / 256), dim3(512), 0, stream, x, ws, bias, y);
}